// Round 2
// baseline (471.344 us; speedup 1.0000x reference)
//
#include <hip/hip_runtime.h>
#include <hip/hip_bf16.h>

typedef __bf16 bf16;
typedef __bf16 bf16x8 __attribute__((ext_vector_type(8)));
typedef float f32x4 __attribute__((ext_vector_type(4)));

#define D_MODEL 512
#define T_SEQ   4096
#define NH      8
#define DH      64
#define M_ROWS  8192   // B*T

// ---------------- kernel 0: dtype detector ----------------------------------
// Reads first 4096 ushorts of x. bf16 N(0,1) data: exponents cluster ~119-130.
// fp32 data read as bf16 halves: low halves have uniform-random exponents.
__global__ __launch_bounds__(64) void detect_dtype(const unsigned short* __restrict__ xr,
                                                   int* __restrict__ flag)
{
  int lane = threadIdx.x;
  int cnt = 0;
  for (int i = lane; i < 4096; i += 64) {
    unsigned short u = xr[i];
    int e = (u >> 7) & 0xFF;
    bool insane = (e >= 133) || (e > 0 && e <= 96) || (e == 0 && (u & 0x7F) != 0);
    cnt += insane ? 1 : 0;
  }
#pragma unroll
  for (int off = 32; off >= 1; off >>= 1) cnt += __shfl_xor(cnt, off);
  if (lane == 0) *flag = (cnt > 400) ? 1 : 0;   // 1 = inputs are fp32
}

// ---------------- kernel 0b: convert x to bf16 -------------------------------
__global__ __launch_bounds__(256) void convert_x(const void* __restrict__ xr,
                                                 const int* __restrict__ flag,
                                                 bf16* __restrict__ xb, int n)
{
  int i = (blockIdx.x * blockDim.x + threadIdx.x) * 4;
  if (i >= n) return;
  if (*flag) {
    float4 v = *(const float4*)((const float*)xr + i);
    __align__(8) bf16 o[4] = {(bf16)v.x, (bf16)v.y, (bf16)v.z, (bf16)v.w};
    *(uint2*)(xb + i) = *(uint2*)o;
  } else {
    *(uint2*)(xb + i) = *(const uint2*)((const bf16*)xr + i);
  }
}

// ---------------- kernel 0c: biases -> fp32 ----------------------------------
__global__ __launch_bounds__(256) void convert_bias(
    const void* b0, const void* b1, const void* b2, const void* b3,
    const int* __restrict__ flag, float* __restrict__ bf)
{
  const void* ps[4] = {b0, b1, b2, b3};
  int fl = *flag;
  for (int t = threadIdx.x; t < 4 * D_MODEL; t += 256) {
    int w = t >> 9, o = t & 511;
    bf[t] = fl ? ((const float*)ps[w])[o] : (float)((const bf16*)ps[w])[o];
  }
}

// ---------------- kernel 1: per-output-channel weight quant-dequant ----------
__global__ __launch_bounds__(256) void qdq_weights(
    const void* __restrict__ Wq, const void* __restrict__ Wk,
    const void* __restrict__ Wv, const void* __restrict__ Wo,
    const int* __restrict__ flag, bf16* __restrict__ out)
{
  int wave = threadIdx.x >> 6, lane = threadIdx.x & 63;
  int gid = blockIdx.x * 4 + wave;           // 0..2047 : weight-row id
  int w = gid >> 9, row = gid & 511;
  const void* W = (w == 0) ? Wq : (w == 1) ? Wk : (w == 2) ? Wv : Wo;
  int fl = *flag;
  float v[8]; float amax = 0.f;
#pragma unroll
  for (int i = 0; i < 8; i++) {
    int idx = row * D_MODEL + lane + 64 * i;
    v[i] = fl ? ((const float*)W)[idx] : (float)((const bf16*)W)[idx];
    amax = fmaxf(amax, fabsf(v[i]));
  }
#pragma unroll
  for (int off = 32; off >= 1; off >>= 1) amax = fmaxf(amax, __shfl_xor(amax, off));
  float s = fmaxf(amax / 127.0f, 1e-8f);     // division: match np semantics
  bf16* dst = out + (size_t)gid * D_MODEL;
#pragma unroll
  for (int i = 0; i < 8; i++) {
    float q = rintf(v[i] / s);               // rintf = round-half-even = np.round
    q = fminf(fmaxf(q, -127.f), 127.f);
    dst[lane + 64*i] = (bf16)(q * s);
  }
}

// ---------------- kernel 2: C = A @ W^T + bias  (A: Mx512 bf16, W: 512x512) --
// 128x128 block tile, 4 waves in 2x2, each wave 64x64 via 4x4 MFMA 16x16x32.
// If Cf != nullptr: write fp32 + block absmax -> atomicMax(amaxp). Else bf16 Cb.
#define LDS_STRIDE 40   // 32 + 8 pad (bf16 elems), keeps 16B alignment
__global__ __launch_bounds__(256) void gemm_bt(
    const bf16* __restrict__ A, const bf16* __restrict__ W,
    const float* __restrict__ bias,
    bf16* __restrict__ Cb, float* __restrict__ Cf, unsigned int* __restrict__ amaxp,
    int M, int K)
{
  __shared__ __align__(16) bf16 As[128 * LDS_STRIDE];
  __shared__ __align__(16) bf16 Bs[128 * LDS_STRIDE];
  __shared__ float wred[4];

  const int tid = threadIdx.x;
  const int wave = tid >> 6, lane = tid & 63;
  const int lr = lane & 15, quad = lane >> 4;
  const int wm = (wave >> 1) * 64, wn = (wave & 1) * 64;
  const int m0 = blockIdx.x * 128, n0 = blockIdx.y * 128;

  f32x4 acc[4][4];
#pragma unroll
  for (int i = 0; i < 4; i++)
#pragma unroll
    for (int j = 0; j < 4; j++) acc[i][j] = f32x4{0.f, 0.f, 0.f, 0.f};

  const int srow = tid >> 2;          // 0..63
  const int sseg = (tid & 3) * 8;     // elem offset 0/8/16/24

  for (int k0 = 0; k0 < K; k0 += 32) {
#pragma unroll
    for (int i = 0; i < 2; i++) {
      int r = srow + i * 64;
      *(uint4*)&As[r * LDS_STRIDE + sseg] = *(const uint4*)(A + (size_t)(m0 + r) * K + k0 + sseg);
      *(uint4*)&Bs[r * LDS_STRIDE + sseg] = *(const uint4*)(W + (size_t)(n0 + r) * K + k0 + sseg);
    }
    __syncthreads();
    bf16x8 af[4], bfr[4];
#pragma unroll
    for (int mt = 0; mt < 4; mt++) af[mt]  = *(bf16x8*)&As[(wm + mt*16 + lr) * LDS_STRIDE + quad*8];
#pragma unroll
    for (int nt = 0; nt < 4; nt++) bfr[nt] = *(bf16x8*)&Bs[(wn + nt*16 + lr) * LDS_STRIDE + quad*8];
#pragma unroll
    for (int mt = 0; mt < 4; mt++)
#pragma unroll
      for (int nt = 0; nt < 4; nt++)
        acc[mt][nt] = __builtin_amdgcn_mfma_f32_16x16x32_bf16(af[mt], bfr[nt], acc[mt][nt], 0, 0, 0);
    __syncthreads();
  }

  float lmax = 0.f;
#pragma unroll
  for (int mt = 0; mt < 4; mt++) {
    int grow = m0 + wm + mt * 16 + quad * 4;
#pragma unroll
    for (int nt = 0; nt < 4; nt++) {
      int gcol = n0 + wn + nt * 16 + lr;
      float b = bias[gcol];
#pragma unroll
      for (int r = 0; r < 4; r++) {
        float v = acc[mt][nt][r] + b;
        if (Cf) { Cf[(size_t)(grow + r) * D_MODEL + gcol] = v; lmax = fmaxf(lmax, fabsf(v)); }
        else    { Cb[(size_t)(grow + r) * D_MODEL + gcol] = (bf16)v; }
      }
    }
  }
  if (Cf) {
#pragma unroll
    for (int off = 32; off >= 1; off >>= 1) lmax = fmaxf(lmax, __shfl_xor(lmax, off));
    if (lane == 0) wred[wave] = lmax;
    __syncthreads();
    if (tid == 0) {
      float m = fmaxf(fmaxf(wred[0], wred[1]), fmaxf(wred[2], wred[3]));
      atomicMax(amaxp, __float_as_uint(m));
    }
  }
}

// ---------------- kernel 3: flash attention ---------------------------------
// grid: (T/64, B*H). block 256 = 4 waves; wave handles 16 q-rows; 64-key chunks.
#define KV_STRIDE 72   // 64 + 8 pad
__global__ __launch_bounds__(256) void attn(
    const bf16* __restrict__ Q, const bf16* __restrict__ K, const bf16* __restrict__ V,
    const int* __restrict__ mask, bf16* __restrict__ ctx)
{
  __shared__ __align__(16) bf16 Ks [64 * KV_STRIDE];
  __shared__ __align__(16) bf16 VTs[64 * KV_STRIDE];   // transposed: VTs[dh][key]
  __shared__ __align__(16) bf16 Pb [4][16 * KV_STRIDE];

  const int tid = threadIdx.x, wave = tid >> 6, lane = tid & 63;
  const int lr = lane & 15, quad = lane >> 4;
  const int bh = blockIdx.y; const int b = bh >> 3, h = bh & 7;
  const int q0 = blockIdx.x * 64 + wave * 16;

  const size_t rowQ = (size_t)(b * T_SEQ + q0 + lr) * D_MODEL + h * DH;
  bf16x8 qf0 = *(const bf16x8*)(Q + rowQ + quad * 8);
  bf16x8 qf1 = *(const bf16x8*)(Q + rowQ + 32 + quad * 8);

  f32x4 O[4];
#pragma unroll
  for (int i = 0; i < 4; i++) O[i] = f32x4{0.f, 0.f, 0.f, 0.f};
  float mrow[4] = {-1e30f, -1e30f, -1e30f, -1e30f};
  float lrow[4] = {0.f, 0.f, 0.f, 0.f};

  const int srow = tid >> 2;        // 0..63 (key row within chunk)
  const int sseg = (tid & 3) * 16;  // dh offset 0/16/32/48
  const int* maskb = mask + b * T_SEQ;

  for (int kb = 0; kb < T_SEQ; kb += 64) {
    { // stage K (row-major) and V (transposed)
      const bf16* gK = K + (size_t)(b * T_SEQ + kb + srow) * D_MODEL + h * DH + sseg;
      const bf16* gV = V + (size_t)(b * T_SEQ + kb + srow) * D_MODEL + h * DH + sseg;
      *(uint4*)&Ks[srow * KV_STRIDE + sseg]     = *(const uint4*)gK;
      *(uint4*)&Ks[srow * KV_STRIDE + sseg + 8] = *(const uint4*)(gK + 8);
      __align__(16) bf16 vtmp[16];
      *(uint4*)&vtmp[0] = *(const uint4*)gV;
      *(uint4*)&vtmp[8] = *(const uint4*)(gV + 8);
#pragma unroll
      for (int e = 0; e < 16; e++) VTs[(sseg + e) * KV_STRIDE + srow] = vtmp[e];
    }
    __syncthreads();

    // S = Q K^T * 1/8, masked
    f32x4 S[4];
#pragma unroll
    for (int nt = 0; nt < 4; nt++) {
      bf16x8 kf0 = *(bf16x8*)&Ks[(nt*16 + lr) * KV_STRIDE + quad*8];
      bf16x8 kf1 = *(bf16x8*)&Ks[(nt*16 + lr) * KV_STRIDE + 32 + quad*8];
      f32x4 z = f32x4{0.f, 0.f, 0.f, 0.f};
      z = __builtin_amdgcn_mfma_f32_16x16x32_bf16(qf1, kf1, z, 0, 0, 0);
      z = __builtin_amdgcn_mfma_f32_16x16x32_bf16(qf0, kf0, z, 0, 0, 0);
      int keep = maskb[kb + nt*16 + lr];
#pragma unroll
      for (int r = 0; r < 4; r++) {
        float v = z[r] * 0.125f;
        S[nt][r] = keep ? v : -1e30f;   // expf(-1e30 - m) underflows to exactly 0
      }
    }

    // online softmax, per q-row r (row = quad*4+r, cols spread over 16-lane group)
    float alpha[4];
#pragma unroll
    for (int r = 0; r < 4; r++) {
      float cm = fmaxf(fmaxf(S[0][r], S[1][r]), fmaxf(S[2][r], S[3][r]));
      cm = fmaxf(cm, __shfl_xor(cm, 1, 16));
      cm = fmaxf(cm, __shfl_xor(cm, 2, 16));
      cm = fmaxf(cm, __shfl_xor(cm, 4, 16));
      cm = fmaxf(cm, __shfl_xor(cm, 8, 16));
      float mn = fmaxf(mrow[r], cm);
      alpha[r] = __expf(mrow[r] - mn);
      mrow[r] = mn;
      float ls = 0.f;
#pragma unroll
      for (int nt = 0; nt < 4; nt++) {
        float p = __expf(S[nt][r] - mn);
        ls += p;
        Pb[wave][(quad*4 + r) * KV_STRIDE + nt*16 + lr] = (bf16)p;  // C-layout -> LDS
      }
      ls += __shfl_xor(ls, 1, 16);
      ls += __shfl_xor(ls, 2, 16);
      ls += __shfl_xor(ls, 4, 16);
      ls += __shfl_xor(ls, 8, 16);
      lrow[r] = lrow[r] * alpha[r] + ls;
    }

    // P @ V : P re-read in A-layout (same wave, DS ops in-order, no barrier)
    bf16x8 pf0 = *(bf16x8*)&Pb[wave][lr * KV_STRIDE + quad*8];
    bf16x8 pf1 = *(bf16x8*)&Pb[wave][lr * KV_STRIDE + 32 + quad*8];
#pragma unroll
    for (int nt = 0; nt < 4; nt++) {
      bf16x8 vf0 = *(bf16x8*)&VTs[(nt*16 + lr) * KV_STRIDE + quad*8];
      bf16x8 vf1 = *(bf16x8*)&VTs[(nt*16 + lr) * KV_STRIDE + 32 + quad*8];
      f32x4 o = O[nt];
#pragma unroll
      for (int r = 0; r < 4; r++) o[r] *= alpha[r];
      o = __builtin_amdgcn_mfma_f32_16x16x32_bf16(pf1, vf1, o, 0, 0, 0);
      o = __builtin_amdgcn_mfma_f32_16x16x32_bf16(pf0, vf0, o, 0, 0, 0);
      O[nt] = o;
    }
    __syncthreads();
  }

  float inv[4];
#pragma unroll
  for (int r = 0; r < 4; r++) inv[r] = 1.0f / lrow[r];
#pragma unroll
  for (int nt = 0; nt < 4; nt++)
#pragma unroll
    for (int r = 0; r < 4; r++) {
      size_t row = (size_t)(b * T_SEQ + q0 + quad*4 + r);
      ctx[row * D_MODEL + h * DH + nt*16 + lr] = (bf16)(O[nt][r] * inv[r]);
    }
}

// ---------------- kernel 4: per-tensor activation quant-dequant --------------
__global__ __launch_bounds__(256) void act_qdq(
    const float* __restrict__ pre, const unsigned int* __restrict__ amaxp,
    const int* __restrict__ flag, void* __restrict__ outv, int n)
{
  int i = blockIdx.x * blockDim.x + threadIdx.x;
  float s = fmaxf(__uint_as_float(*amaxp) / 127.0f, 1e-8f);
  if (i < n) {
    float v = pre[i];
    float q = rintf(v / s);
    q = fminf(fmaxf(q, -127.f), 127.f);
    float o = q * s;
    if (*flag) ((float*)outv)[i] = o;
    else       ((bf16*)outv)[i] = (bf16)o;
  }
}

// ---------------- launch -----------------------------------------------------
extern "C" void kernel_launch(void* const* d_in, const int* in_sizes, int n_in,
                              void* d_out, int out_size, void* d_ws, size_t ws_size,
                              hipStream_t stream) {
  const void* x    = d_in[0];
  const int*  mask = (const int*)d_in[1];
  const void* Wq = d_in[2]; const void* bq = d_in[3];
  const void* Wk = d_in[4]; const void* bk = d_in[5];
  const void* Wv = d_in[6]; const void* bv = d_in[7];
  const void* Wo = d_in[8]; const void* bo = d_in[9];

  char* ws = (char*)d_ws;
  // layout (bytes):
  int*  flag  = (int*)(ws + 0);
  unsigned int* amax = (unsigned int*)(ws + 64);
  float* biasf = (float*)(ws + 1024);                 // 4x512 fp32 (8 KB)
  bf16* Wt  = (bf16*)(ws + 16384);                    // 4x512x512 bf16 (2 MB) -> ends 2,113,536
  bf16* xb  = (bf16*)(ws + 4194304);                  // 8192x512 bf16 (8 MB)  -> ends 12,582,912
  bf16* Qm  = (bf16*)(ws + 12582912);                 // 8 MB
  bf16* Km  = (bf16*)(ws + 20971520);                 // 8 MB
  bf16* Vm  = (bf16*)(ws + 29360128);                 // 8 MB -> ends 37,748,736
  bf16* Cm  = (bf16*)(ws + 4194304);                  // overlays xb (dead after QKV gemms)
  float* pre = (float*)(ws + 12582912);               // 16 MB, overlays Qm+Km (dead after attn)
  // total ws required: 37,748,736 bytes (~36 MB)

  hipMemsetAsync(amax, 0, 4, stream);
  detect_dtype<<<1, 64, 0, stream>>>((const unsigned short*)x, flag);
  convert_x<<<4096, 256, 0, stream>>>(x, flag, xb, M_ROWS * D_MODEL);
  convert_bias<<<1, 256, 0, stream>>>(bq, bk, bv, bo, flag, biasf);
  qdq_weights<<<512, 256, 0, stream>>>(Wq, Wk, Wv, Wo, flag, Wt);
  gemm_bt<<<dim3(64, 4), 256, 0, stream>>>(xb, Wt + 0*262144, biasf + 0,    Qm, nullptr, nullptr, M_ROWS, D_MODEL);
  gemm_bt<<<dim3(64, 4), 256, 0, stream>>>(xb, Wt + 1*262144, biasf + 512,  Km, nullptr, nullptr, M_ROWS, D_MODEL);
  gemm_bt<<<dim3(64, 4), 256, 0, stream>>>(xb, Wt + 2*262144, biasf + 1024, Vm, nullptr, nullptr, M_ROWS, D_MODEL);
  attn<<<dim3(64, 16), 256, 0, stream>>>(Qm, Km, Vm, mask, Cm);
  gemm_bt<<<dim3(64, 4), 256, 0, stream>>>(Cm, Wt + 3*262144, biasf + 1536, nullptr, pre, amax, M_ROWS, D_MODEL);
  act_qdq<<<16384, 256, 0, stream>>>(pre, amax, flag, d_out, M_ROWS * D_MODEL);
}

// Round 3
// 344.449 us; speedup vs baseline: 1.3684x; 1.3684x over previous
//
#include <hip/hip_runtime.h>
#include <hip/hip_bf16.h>

typedef __bf16 bf16;
typedef __bf16 bf16x8 __attribute__((ext_vector_type(8)));
typedef __bf16 bf16x4v __attribute__((ext_vector_type(4)));
typedef float f32x4 __attribute__((ext_vector_type(4)));

#define D_MODEL 512
#define T_SEQ   4096
#define NH      8
#define DH      64
#define M_ROWS  8192   // B*T

// ---------------- kernel 0: dtype detector ----------------------------------
__global__ __launch_bounds__(64) void detect_dtype(const unsigned short* __restrict__ xr,
                                                   int* __restrict__ flag)
{
  int lane = threadIdx.x;
  int cnt = 0;
  for (int i = lane; i < 4096; i += 64) {
    unsigned short u = xr[i];
    int e = (u >> 7) & 0xFF;
    bool insane = (e >= 133) || (e > 0 && e <= 96) || (e == 0 && (u & 0x7F) != 0);
    cnt += insane ? 1 : 0;
  }
#pragma unroll
  for (int off = 32; off >= 1; off >>= 1) cnt += __shfl_xor(cnt, off);
  if (lane == 0) *flag = (cnt > 400) ? 1 : 0;   // 1 = inputs are fp32
}

// ---------------- kernel 0b: convert x to bf16 -------------------------------
__global__ __launch_bounds__(256) void convert_x(const void* __restrict__ xr,
                                                 const int* __restrict__ flag,
                                                 bf16* __restrict__ xb, int n)
{
  int i = (blockIdx.x * blockDim.x + threadIdx.x) * 4;
  if (i >= n) return;
  if (*flag) {
    float4 v = *(const float4*)((const float*)xr + i);
    __align__(8) bf16 o[4] = {(bf16)v.x, (bf16)v.y, (bf16)v.z, (bf16)v.w};
    *(uint2*)(xb + i) = *(uint2*)o;
  } else {
    *(uint2*)(xb + i) = *(const uint2*)((const bf16*)xr + i);
  }
}

// ---------------- kernel 0c: biases -> fp32 ----------------------------------
__global__ __launch_bounds__(256) void convert_bias(
    const void* b0, const void* b1, const void* b2, const void* b3,
    const int* __restrict__ flag, float* __restrict__ bf)
{
  const void* ps[4] = {b0, b1, b2, b3};
  int fl = *flag;
  for (int t = threadIdx.x; t < 4 * D_MODEL; t += 256) {
    int w = t >> 9, o = t & 511;
    bf[t] = fl ? ((const float*)ps[w])[o] : (float)((const bf16*)ps[w])[o];
  }
}

// ---------------- kernel 1: per-output-channel weight quant-dequant ----------
__global__ __launch_bounds__(256) void qdq_weights(
    const void* __restrict__ Wq, const void* __restrict__ Wk,
    const void* __restrict__ Wv, const void* __restrict__ Wo,
    const int* __restrict__ flag, bf16* __restrict__ out)
{
  int wave = threadIdx.x >> 6, lane = threadIdx.x & 63;
  int gid = blockIdx.x * 4 + wave;
  int w = gid >> 9, row = gid & 511;
  const void* W = (w == 0) ? Wq : (w == 1) ? Wk : (w == 2) ? Wv : Wo;
  int fl = *flag;
  float v[8]; float amax = 0.f;
#pragma unroll
  for (int i = 0; i < 8; i++) {
    int idx = row * D_MODEL + lane + 64 * i;
    v[i] = fl ? ((const float*)W)[idx] : (float)((const bf16*)W)[idx];
    amax = fmaxf(amax, fabsf(v[i]));
  }
#pragma unroll
  for (int off = 32; off >= 1; off >>= 1) amax = fmaxf(amax, __shfl_xor(amax, off));
  float s = fmaxf(amax / 127.0f, 1e-8f);
  bf16* dst = out + (size_t)gid * D_MODEL;
#pragma unroll
  for (int i = 0; i < 8; i++) {
    float q = rintf(v[i] / s);
    q = fminf(fmaxf(q, -127.f), 127.f);
    dst[lane + 64*i] = (bf16)(q * s);
  }
}

// ---------------- kernel 2: C = A @ W^T + bias -------------------------------
// Modes: Cb = row-major bf16; Ct = TRANSPOSED bf16 (Ct[col*M+row], packed x4);
//        Cf = fp32 + global absmax.
#define LDS_STRIDE 40
__global__ __launch_bounds__(256) void gemm_bt(
    const bf16* __restrict__ A, const bf16* __restrict__ W,
    const float* __restrict__ bias,
    bf16* __restrict__ Cb, bf16* __restrict__ Ct,
    float* __restrict__ Cf, unsigned int* __restrict__ amaxp,
    int M, int K)
{
  __shared__ __align__(16) bf16 As[128 * LDS_STRIDE];
  __shared__ __align__(16) bf16 Bs[128 * LDS_STRIDE];
  __shared__ float wred[4];

  const int tid = threadIdx.x;
  const int wave = tid >> 6, lane = tid & 63;
  const int lr = lane & 15, quad = lane >> 4;
  const int wm = (wave >> 1) * 64, wn = (wave & 1) * 64;
  const int m0 = blockIdx.x * 128, n0 = blockIdx.y * 128;

  f32x4 acc[4][4];
#pragma unroll
  for (int i = 0; i < 4; i++)
#pragma unroll
    for (int j = 0; j < 4; j++) acc[i][j] = f32x4{0.f, 0.f, 0.f, 0.f};

  const int srow = tid >> 2;
  const int sseg = (tid & 3) * 8;

  for (int k0 = 0; k0 < K; k0 += 32) {
#pragma unroll
    for (int i = 0; i < 2; i++) {
      int r = srow + i * 64;
      *(uint4*)&As[r * LDS_STRIDE + sseg] = *(const uint4*)(A + (size_t)(m0 + r) * K + k0 + sseg);
      *(uint4*)&Bs[r * LDS_STRIDE + sseg] = *(const uint4*)(W + (size_t)(n0 + r) * K + k0 + sseg);
    }
    __syncthreads();
    bf16x8 af[4], bfr[4];
#pragma unroll
    for (int mt = 0; mt < 4; mt++) af[mt]  = *(bf16x8*)&As[(wm + mt*16 + lr) * LDS_STRIDE + quad*8];
#pragma unroll
    for (int nt = 0; nt < 4; nt++) bfr[nt] = *(bf16x8*)&Bs[(wn + nt*16 + lr) * LDS_STRIDE + quad*8];
#pragma unroll
    for (int mt = 0; mt < 4; mt++)
#pragma unroll
      for (int nt = 0; nt < 4; nt++)
        acc[mt][nt] = __builtin_amdgcn_mfma_f32_16x16x32_bf16(af[mt], bfr[nt], acc[mt][nt], 0, 0, 0);
    __syncthreads();
  }

  float lmax = 0.f;
#pragma unroll
  for (int mt = 0; mt < 4; mt++) {
    int grow = m0 + wm + mt * 16 + quad * 4;
#pragma unroll
    for (int nt = 0; nt < 4; nt++) {
      int gcol = n0 + wn + nt * 16 + lr;
      float b = bias[gcol];
      if (Ct) {                     // transposed packed store: Ct[gcol][grow..+3]
        bf16x4v pk;
#pragma unroll
        for (int r = 0; r < 4; r++) pk[r] = (bf16)(acc[mt][nt][r] + b);
        *(bf16x4v*)(Ct + (size_t)gcol * M + grow) = pk;
      } else {
#pragma unroll
        for (int r = 0; r < 4; r++) {
          float v = acc[mt][nt][r] + b;
          if (Cf) { Cf[(size_t)(grow + r) * D_MODEL + gcol] = v; lmax = fmaxf(lmax, fabsf(v)); }
          else    { Cb[(size_t)(grow + r) * D_MODEL + gcol] = (bf16)v; }
        }
      }
    }
  }
  if (Cf) {
#pragma unroll
    for (int off = 32; off >= 1; off >>= 1) lmax = fmaxf(lmax, __shfl_xor(lmax, off));
    if (lane == 0) wred[wave] = lmax;
    __syncthreads();
    if (tid == 0) {
      float m = fmaxf(fmaxf(wred[0], wred[1]), fmaxf(wred[2], wred[3]));
      atomicMax(amaxp, __float_as_uint(m));
    }
  }
}

// ---------------- kernel 3: flash attention, S^T formulation -----------------
// grid (T/64, B*H), block 256 = 4 waves; wave = 16 q-rows; 64-key chunks.
// S^T = K·Q^T : A-frag = K rows (LDS), B-frag = Q rows (global).
// Softmax per-lane (col q = lane&15), cross-quad via 2 shfl_xor.
// P^T packed b64 -> Pb; PV: A = P (Pb), B = V (from pre-transposed VT in LDS).
#define KV_STRIDE 72   // 144B rows: 36 banks ≡ 4 mod 32 -> conflict-free b128 reads
__global__ __launch_bounds__(256) void attn(
    const bf16* __restrict__ Q, const bf16* __restrict__ K, const bf16* __restrict__ VT,
    const int* __restrict__ mask, bf16* __restrict__ ctx)
{
  __shared__ __align__(16) bf16 Ks [64 * KV_STRIDE];
  __shared__ __align__(16) bf16 VTs[64 * KV_STRIDE];   // VTs[dh][key]
  __shared__ __align__(16) bf16 Pb [4][16 * KV_STRIDE];
  __shared__ __align__(16) float Msk[64];

  const int tid = threadIdx.x, wave = tid >> 6, lane = tid & 63;
  const int lr = lane & 15, quad = lane >> 4;
  const int bh = blockIdx.y; const int b = bh >> 3, h = bh & 7;
  const int q0 = blockIdx.x * 64 + wave * 16;

  // Q as B-frag: B[k=dh=quad*8+j][n=q=lr]
  const size_t rowQ = (size_t)(b * T_SEQ + q0 + lr) * D_MODEL + h * DH;
  bf16x8 qf0 = *(const bf16x8*)(Q + rowQ + quad * 8);
  bf16x8 qf1 = *(const bf16x8*)(Q + rowQ + 32 + quad * 8);

  f32x4 O[4];   // O[nt] : O[q=4quad+r][dh=16nt+lr]
#pragma unroll
  for (int i = 0; i < 4; i++) O[i] = f32x4{0.f, 0.f, 0.f, 0.f};
  float mrow = -1e30f, lrow = 0.f;   // per-lane state for q = lr

  const int srow = tid >> 2;        // 0..63
  const int sseg = (tid & 3) * 16;  // 0/16/32/48
  const int* maskb = mask + b * T_SEQ;

  for (int kb = 0; kb < T_SEQ; kb += 64) {
    { // stage K rows + VT rows (both clean uint4, conflict-free)
      const bf16* gK = K  + (size_t)(b * T_SEQ + kb + srow) * D_MODEL + h * DH + sseg;
      const bf16* gV = VT + (size_t)(h * DH + srow) * M_ROWS + b * T_SEQ + kb + sseg;
      *(uint4*)&Ks [srow * KV_STRIDE + sseg]     = *(const uint4*)gK;
      *(uint4*)&Ks [srow * KV_STRIDE + sseg + 8] = *(const uint4*)(gK + 8);
      *(uint4*)&VTs[srow * KV_STRIDE + sseg]     = *(const uint4*)gV;
      *(uint4*)&VTs[srow * KV_STRIDE + sseg + 8] = *(const uint4*)(gV + 8);
      if (tid < 64) Msk[tid] = maskb[kb + tid] ? 0.f : -1e30f;
    }
    __syncthreads();

    // S^T tiles: S^T[key=16mt+4quad+r][q=lr]
    f32x4 S[4];
#pragma unroll
    for (int mt = 0; mt < 4; mt++) {
      bf16x8 kf0 = *(bf16x8*)&Ks[(mt*16 + lr) * KV_STRIDE + quad*8];
      bf16x8 kf1 = *(bf16x8*)&Ks[(mt*16 + lr) * KV_STRIDE + 32 + quad*8];
      f32x4 z = f32x4{0.f, 0.f, 0.f, 0.f};
      z = __builtin_amdgcn_mfma_f32_16x16x32_bf16(kf1, qf1, z, 0, 0, 0);
      z = __builtin_amdgcn_mfma_f32_16x16x32_bf16(kf0, qf0, z, 0, 0, 0);
      f32x4 mk = *(f32x4*)&Msk[mt*16 + quad*4];
#pragma unroll
      for (int r = 0; r < 4; r++) S[mt][r] = z[r] * 0.125f + mk[r];
    }

    // online softmax (per-lane over 16 keys, then across quads)
    float cm = -1e30f;
#pragma unroll
    for (int mt = 0; mt < 4; mt++)
#pragma unroll
      for (int r = 0; r < 4; r++) cm = fmaxf(cm, S[mt][r]);
    cm = fmaxf(cm, __shfl_xor(cm, 16));
    cm = fmaxf(cm, __shfl_xor(cm, 32));
    float mn = fmaxf(mrow, cm);
    float alpha = __expf(mrow - mn);
    mrow = mn;
    float ls = 0.f;
#pragma unroll
    for (int mt = 0; mt < 4; mt++) {
      bf16x4v pk;
#pragma unroll
      for (int r = 0; r < 4; r++) {
        float p = __expf(S[mt][r] - mn);
        ls += p;
        pk[r] = (bf16)p;
      }
      *(bf16x4v*)&Pb[wave][lr * KV_STRIDE + mt*16 + quad*4] = pk;  // packed b64
    }
    ls += __shfl_xor(ls, 16);
    ls += __shfl_xor(ls, 32);
    lrow = lrow * alpha + ls;

    // alpha for O rows q = 4quad+r (state lives at lane lr=q)
    float aO[4];
#pragma unroll
    for (int r = 0; r < 4; r++) aO[r] = __shfl(alpha, quad*4 + r);

    // PV: A = P[m=q=lr][k=key] from Pb (same-wave ds order), B = V from VTs
    bf16x8 pf0 = *(bf16x8*)&Pb[wave][lr * KV_STRIDE + quad*8];
    bf16x8 pf1 = *(bf16x8*)&Pb[wave][lr * KV_STRIDE + 32 + quad*8];
#pragma unroll
    for (int nt = 0; nt < 4; nt++) {
      bf16x8 vf0 = *(bf16x8*)&VTs[(nt*16 + lr) * KV_STRIDE + quad*8];
      bf16x8 vf1 = *(bf16x8*)&VTs[(nt*16 + lr) * KV_STRIDE + 32 + quad*8];
      f32x4 o = O[nt];
#pragma unroll
      for (int r = 0; r < 4; r++) o[r] *= aO[r];
      o = __builtin_amdgcn_mfma_f32_16x16x32_bf16(pf1, vf1, o, 0, 0, 0);
      o = __builtin_amdgcn_mfma_f32_16x16x32_bf16(pf0, vf0, o, 0, 0, 0);
      O[nt] = o;
    }
    __syncthreads();
  }

  float linv = 1.0f / lrow;
  float lO[4];
#pragma unroll
  for (int r = 0; r < 4; r++) lO[r] = __shfl(linv, quad*4 + r);
#pragma unroll
  for (int nt = 0; nt < 4; nt++)
#pragma unroll
    for (int r = 0; r < 4; r++) {
      size_t row = (size_t)(b * T_SEQ + q0 + quad*4 + r);
      ctx[row * D_MODEL + h * DH + nt*16 + lr] = (bf16)(O[nt][r] * lO[r]);
    }
}

// ---------------- kernel 4: per-tensor activation quant-dequant --------------
__global__ __launch_bounds__(256) void act_qdq(
    const float* __restrict__ pre, const unsigned int* __restrict__ amaxp,
    const int* __restrict__ flag, void* __restrict__ outv, int n)
{
  int i = blockIdx.x * blockDim.x + threadIdx.x;
  float s = fmaxf(__uint_as_float(*amaxp) / 127.0f, 1e-8f);
  if (i < n) {
    float v = pre[i];
    float q = rintf(v / s);
    q = fminf(fmaxf(q, -127.f), 127.f);
    float o = q * s;
    if (*flag) ((float*)outv)[i] = o;
    else       ((bf16*)outv)[i] = (bf16)o;
  }
}

// ---------------- launch -----------------------------------------------------
extern "C" void kernel_launch(void* const* d_in, const int* in_sizes, int n_in,
                              void* d_out, int out_size, void* d_ws, size_t ws_size,
                              hipStream_t stream) {
  const void* x    = d_in[0];
  const int*  mask = (const int*)d_in[1];
  const void* Wq = d_in[2]; const void* bq = d_in[3];
  const void* Wk = d_in[4]; const void* bk = d_in[5];
  const void* Wv = d_in[6]; const void* bv = d_in[7];
  const void* Wo = d_in[8]; const void* bo = d_in[9];

  char* ws = (char*)d_ws;
  int*  flag  = (int*)(ws + 0);
  unsigned int* amax = (unsigned int*)(ws + 64);
  float* biasf = (float*)(ws + 1024);
  bf16* Wt  = (bf16*)(ws + 16384);                    // 2 MB
  bf16* xb  = (bf16*)(ws + 4194304);                  // 8 MB
  bf16* Qm  = (bf16*)(ws + 12582912);                 // 8 MB
  bf16* Km  = (bf16*)(ws + 20971520);                 // 8 MB
  bf16* VT  = (bf16*)(ws + 29360128);                 // 8 MB: VT[ch][token] 512x8192
  bf16* Cm  = (bf16*)(ws + 4194304);                  // overlays xb
  float* pre = (float*)(ws + 12582912);               // overlays Qm+Km

  hipMemsetAsync(amax, 0, 4, stream);
  detect_dtype<<<1, 64, 0, stream>>>((const unsigned short*)x, flag);
  convert_x<<<4096, 256, 0, stream>>>(x, flag, xb, M_ROWS * D_MODEL);
  convert_bias<<<1, 256, 0, stream>>>(bq, bk, bv, bo, flag, biasf);
  qdq_weights<<<512, 256, 0, stream>>>(Wq, Wk, Wv, Wo, flag, Wt);
  gemm_bt<<<dim3(64, 4), 256, 0, stream>>>(xb, Wt + 0*262144, biasf + 0,    Qm, nullptr, nullptr, nullptr, M_ROWS, D_MODEL);
  gemm_bt<<<dim3(64, 4), 256, 0, stream>>>(xb, Wt + 1*262144, biasf + 512,  Km, nullptr, nullptr, nullptr, M_ROWS, D_MODEL);
  gemm_bt<<<dim3(64, 4), 256, 0, stream>>>(xb, Wt + 2*262144, biasf + 1024, nullptr, VT, nullptr, nullptr, M_ROWS, D_MODEL);
  attn<<<dim3(64, 16), 256, 0, stream>>>(Qm, Km, VT, mask, Cm);
  gemm_bt<<<dim3(64, 4), 256, 0, stream>>>(Cm, Wt + 3*262144, biasf + 1536, nullptr, nullptr, pre, amax, M_ROWS, D_MODEL);
  act_qdq<<<16384, 256, 0, stream>>>(pre, amax, flag, d_out, M_ROWS * D_MODEL);
}